// Round 7
// baseline (299.688 us; speedup 1.0000x reference)
//
#include <hip/hip_runtime.h>
#include <hip/hip_bf16.h>
#include <type_traits>

// ---------------------------------------------------------------------------
// Problem constants
//   x: (8,128,128,256) f32   z: (8,64,64,256) f32   mask: (1,8,8,8,256,64) int
//   Wq (256,256) bq(256)  Wkv (256,512) bkv(512)  Wo (256,256) bo(256)
//   rel_table (900,8) f32   out: (8,128,128,256) f32
// ---------------------------------------------------------------------------

typedef __attribute__((ext_vector_type(8))) short short8v;     // MFMA bf16 frag
typedef __attribute__((ext_vector_type(4))) float f32x4;       // MFMA acc
typedef __attribute__((ext_vector_type(8))) unsigned short ushort8v;
typedef unsigned long long u64;

#define DEV __device__ __forceinline__

DEV unsigned short f2bf(float f) {               // round-to-nearest-even f32->bf16
    union { float f; unsigned u; } v; v.f = f;
    unsigned r = v.u + 0x7FFFu + ((v.u >> 16) & 1u);
    return (unsigned short)(r >> 16);
}

DEV short8v cvt_f32x8(const float4 lo, const float4 hi) {      // 8 f32 -> 8 bf16
    union U { __hip_bfloat162 h[4]; short8v s; } u;
    u.h[0] = __float22bfloat162_rn(float2{lo.x, lo.y});
    u.h[1] = __float22bfloat162_rn(float2{lo.z, lo.w});
    u.h[2] = __float22bfloat162_rn(float2{hi.x, hi.y});
    u.h[3] = __float22bfloat162_rn(float2{hi.z, hi.w});
    return u.s;
}

DEV uint2 pack4(f32x4 v) {                       // 4 f32 -> 4 bf16 (8 B)
    union { __hip_bfloat162 h; unsigned u; } a, b;
    a.h = __float22bfloat162_rn(float2{v[0], v[1]});
    b.h = __float22bfloat162_rn(float2{v[2], v[3]});
    return uint2{a.u, b.u};
}

#define ATT_SCALE 0.17677669529663687f           // 1/sqrt(32)

// ---------------------------------------------------------------------------
// Prep kernels
// ---------------------------------------------------------------------------
__global__ void prep_weights(const float* __restrict__ Wq, const float* __restrict__ Wkv,
                             const float* __restrict__ Wo,
                             unsigned short* __restrict__ WqT, unsigned short* __restrict__ WkvT,
                             unsigned short* __restrict__ WoT) {
    int idx = blockIdx.x * 256 + threadIdx.x;            // 262144 total
    if (idx < 65536) {
        int n = idx >> 8, k = idx & 255;
        WqT[idx] = f2bf(Wq[k * 256 + n] * ATT_SCALE);
    } else if (idx < 196608) {
        int i = idx - 65536;
        int n = i >> 8, k = i & 255;
        WkvT[i] = f2bf(Wkv[k * 512 + n]);
    } else {
        int i = idx - 196608;
        int n = i >> 8, k = i & 255;
        WoT[i] = f2bf(Wo[k * 256 + n]);
    }
}

__global__ void prep_bias(const float* __restrict__ rel_table, const float* __restrict__ bq,
                          float* __restrict__ biasb, float* __restrict__ bqs) {
    int idx = blockIdx.x * 256 + threadIdx.x;
    if (idx < 131072) {
        int head = idx >> 14;
        int q = (idx >> 6) & 255;
        int k = idx & 63;
        int qi = q >> 4, qj = q & 15;
        int ki = k >> 3, kj = k & 7;
        int r0 = qi - 2 * ki + 14, r1 = qj - 2 * kj + 14;
        biasb[idx] = rel_table[(r0 * 30 + r1) * 8 + head];
    } else if (idx < 131328) {
        int i = idx - 131072;
        bqs[i] = bq[i] * ATT_SCALE;
    }
}

__global__ void prep_mask(const int* __restrict__ mask, u64* __restrict__ mp) {
    int idx = blockIdx.x * 256 + threadIdx.x;            // 131072 rows
    const int4* src = reinterpret_cast<const int4*>(mask + (size_t)idx * 64);
    u64 bits = 0;
#pragma unroll
    for (int c = 0; c < 16; ++c) {
        int4 v = src[c];
        if (v.x) bits |= 1ull << (c * 4 + 0);
        if (v.y) bits |= 1ull << (c * 4 + 1);
        if (v.z) bits |= 1ull << (c * 4 + 2);
        if (v.w) bits |= 1ull << (c * 4 + 3);
    }
    mp[idx] = bits;
}

// ---------------------------------------------------------------------------
// KV-proj GEMM (R3 structure). K part -> Kb [b*4096+sp][256] bf16 (un-rolled).
// V part -> Vg [b][d=256][4096] bf16, TRANSPOSED + PRE-ROLLED:
//   Vg[b][d][p*64+q] = V[b][(p+4)&63][(q+4)&63][d]
// so fused attention's PV A-fragments are 16B-contiguous direct global loads.
// Epilogue j-groups are 4-aligned in spatial -> rolled q stays 4-contiguous
// -> packed uint2 (8B) writes.
// ---------------------------------------------------------------------------
__global__ __launch_bounds__(256) void gemm_kv(
    const float* __restrict__ Af, const unsigned short* __restrict__ BT,
    const float* __restrict__ bias, unsigned short* __restrict__ Kb,
    unsigned short* __restrict__ Vg, int K)
{
    __shared__ __align__(16) unsigned char As[2][8192];   // 128 rows x 64B
    __shared__ __align__(16) unsigned char Bs[2][8192];

    const int tid = threadIdx.x;
    const int mb = blockIdx.y * 128, nb = blockIdx.x * 128;
    const int w = tid >> 6, lane = tid & 63, lr = lane & 15, lg = lane >> 4;
    const int wm = (w >> 1) * 64, wn = (w & 1) * 64;

    const int cr0 = (w << 5) + (lane >> 2);
    const int csp = lane & 3;
    const int cs0 = csp ^ ((cr0 >> 1) & 3);
    const int cs1 = csp ^ (((cr0 + 16) >> 1) & 3);

    auto stageB = [&](int buf, int kb) {
        __builtin_amdgcn_global_load_lds(
            (const __attribute__((address_space(1))) void*)(BT + (size_t)(nb + cr0) * K + kb + cs0 * 8),
            (__attribute__((address_space(3))) void*)(&Bs[buf][w << 11]), 16, 0, 0);
        __builtin_amdgcn_global_load_lds(
            (const __attribute__((address_space(1))) void*)(BT + (size_t)(nb + cr0 + 16) * K + kb + cs1 * 8),
            (__attribute__((address_space(3))) void*)(&Bs[buf][(w << 11) + 1024]), 16, 0, 0);
    };

    float4 areg[2][2];
    auto loadA = [&](int kb) {
#pragma unroll
        for (int i = 0; i < 2; ++i) {
            int flat = tid + (i << 8);
            int r = flat >> 2, sp = flat & 3;
            int s = sp ^ ((r >> 1) & 3);
            const float* src = Af + (size_t)(mb + r) * K + kb + s * 8;
            areg[i][0] = *reinterpret_cast<const float4*>(src);
            areg[i][1] = *reinterpret_cast<const float4*>(src + 4);
        }
    };
    auto writeA = [&](int buf) {
#pragma unroll
        for (int i = 0; i < 2; ++i) {
            int flat = tid + (i << 8);
            int r = flat >> 2, sp = flat & 3;
            ushort8v u = { f2bf(areg[i][0].x), f2bf(areg[i][0].y),
                           f2bf(areg[i][0].z), f2bf(areg[i][0].w),
                           f2bf(areg[i][1].x), f2bf(areg[i][1].y),
                           f2bf(areg[i][1].z), f2bf(areg[i][1].w) };
            *reinterpret_cast<ushort8v*>(&As[buf][r * 64 + sp * 16]) = u;
        }
    };
    auto rdA = [&](int buf, int row) -> short8v {
        int swz = (lg ^ ((row >> 1) & 3)) << 4;
        return *reinterpret_cast<const short8v*>(&As[buf][row * 64 + swz]);
    };
    auto rdB = [&](int buf, int row) -> short8v {
        int swz = (lg ^ ((row >> 1) & 3)) << 4;
        return *reinterpret_cast<const short8v*>(&Bs[buf][row * 64 + swz]);
    };

    f32x4 acc[4][4];
#pragma unroll
    for (int i = 0; i < 4; ++i)
#pragma unroll
        for (int j = 0; j < 4; ++j) acc[i][j] = {0.f, 0.f, 0.f, 0.f};

    loadA(0); stageB(0, 0); writeA(0);
    __syncthreads();

    const int NT = K >> 5;
    int cur = 0;
    for (int t = 0; t < NT; ++t) {
        if (t + 1 < NT) { loadA((t + 1) << 5); stageB(cur ^ 1, (t + 1) << 5); }
        short8v af[4], bfr[4];
#pragma unroll
        for (int mt = 0; mt < 4; ++mt) af[mt] = rdA(cur, wm + mt * 16 + lr);
#pragma unroll
        for (int nt = 0; nt < 4; ++nt) bfr[nt] = rdB(cur, wn + nt * 16 + lr);
#pragma unroll
        for (int mt = 0; mt < 4; ++mt)
#pragma unroll
            for (int nt = 0; nt < 4; ++nt)
                acc[mt][nt] = __builtin_amdgcn_mfma_f32_16x16x32_bf16(
                    af[mt], bfr[nt], acc[mt][nt], 0, 0, 0);
        if (t + 1 < NT) writeA(cur ^ 1);
        __syncthreads();
        cur ^= 1;
    }

#pragma unroll
    for (int mt = 0; mt < 4; ++mt) {
        int row0 = mb + wm + mt * 16 + lg * 4;
        int bb_ = row0 >> 12;
        int kr  = (row0 >> 6) & 63;
        int kc0 = row0 & 63;                      // 4-aligned
        int p   = (kr - 4) & 63;
        int q0  = (kc0 - 4) & 63;                 // stays 4-aligned
#pragma unroll
        for (int nt = 0; nt < 4; ++nt) {
            int col = nb + wn + nt * 16 + lr;
            f32x4 v;
#pragma unroll
            for (int j = 0; j < 4; ++j) v[j] = acc[mt][nt][j] + bias[col];
            if (col < 256) {                      // uniform per block
#pragma unroll
                for (int j = 0; j < 4; ++j)
                    Kb[(size_t)(row0 + j) * 256 + col] = f2bf(v[j]);
            } else {
                uint2 pk = pack4(v);
                *reinterpret_cast<uint2*>(
                    Vg + (((size_t)bb_ * 256 + (col - 256)) << 12) + p * 64 + q0) = pk;
            }
        }
    }
}

// ---------------------------------------------------------------------------
// Mega-fused kernel v2: Q-proj + 8-head window attention + O-proj.
// Block = (qblk 0..3, win 0..63, b 0..7), 256 thr / 4 waves; 64 q rows.
// LDS: Qs/Os 8 planes x [64q][64B] = 32KB + Ps 2 planes = 8KB -> 40KB
//  -> exactly 4 blocks/CU.  V is read DIRECT from pre-transposed Vg (no LDS
// staging, no transpose).  K direct from Kb.  2 barriers total.
// ---------------------------------------------------------------------------
__global__ __launch_bounds__(256, 4) void fused_attn(
    const float* __restrict__ x, const unsigned short* __restrict__ Kb,
    const unsigned short* __restrict__ Vg,
    const unsigned short* __restrict__ WqT, const unsigned short* __restrict__ WoT,
    const float* __restrict__ bqs, const float* __restrict__ bo,
    const u64* __restrict__ maskp, const float* __restrict__ biasb,
    float* __restrict__ out)
{
    __shared__ __align__(16) unsigned char L[40960];
    // Qs/Os: L + kt*4096          kt = 0..7   [64 q][64 B]
    // Ps:    L + 32768 + kc*4096  kc = 0..1   [64 q][64 B]

    const int tid = threadIdx.x;
    const int w = tid >> 6, lane = tid & 63, lr = lane & 15, lg = lane >> 4;
    const int qblk = blockIdx.x, win = blockIdx.y, b = blockIdx.z;
    const int wi = win >> 3, wj = win & 7;

    // ---- phase 1: Q = x @ Wq(scaled) + bq.  Wave owns n in [w*64, w*64+64) --
    f32x4 acc[16];
#pragma unroll
    for (int i = 0; i < 16; ++i) acc[i] = {0.f, 0.f, 0.f, 0.f};

    const unsigned short* wqb = WqT + (size_t)(w * 64 + lr) * 256 + lg * 8;
    const float* xr[4];
#pragma unroll
    for (int qt = 0; qt < 4; ++qt) {
        int gr = (wi * 16 + qblk * 4 + qt + 8) & 127;
        int gc = (wj * 16 + lr + 8) & 127;
        xr[qt] = x + ((size_t)((b * 128 + gr) * 128 + gc)) * 256 + lg * 8;
    }
#pragma unroll
    for (int kt = 0; kt < 8; ++kt) {
        short8v wqf[4], xf[4];
#pragma unroll
        for (int nt = 0; nt < 4; ++nt)
            wqf[nt] = *reinterpret_cast<const short8v*>(wqb + nt * 4096 + kt * 32);
#pragma unroll
        for (int qt = 0; qt < 4; ++qt) {
            float4 lo = *reinterpret_cast<const float4*>(xr[qt] + kt * 32);
            float4 hi = *reinterpret_cast<const float4*>(xr[qt] + kt * 32 + 4);
            xf[qt] = cvt_f32x8(lo, hi);
        }
        __builtin_amdgcn_s_setprio(1);
#pragma unroll
        for (int nt = 0; nt < 4; ++nt)
#pragma unroll
            for (int qt = 0; qt < 4; ++qt)
                acc[nt * 4 + qt] = __builtin_amdgcn_mfma_f32_16x16x32_bf16(
                    wqf[nt], xf[qt], acc[nt * 4 + qt], 0, 0, 0);
        __builtin_amdgcn_s_setprio(0);
    }
#pragma unroll
    for (int nt = 0; nt < 4; ++nt) {
        int n0 = w * 64 + nt * 16 + lg * 4;
        f32x4 bq4 = *reinterpret_cast<const f32x4*>(bqs + n0);
        unsigned char* pl = L + (w * 2 + (nt >> 1)) * 4096;
        int cby = (nt & 1) * 32 + lg * 8;
#pragma unroll
        for (int qt = 0; qt < 4; ++qt) {
            int qr = qt * 16 + lr;
            uint2 pk = pack4(acc[nt * 4 + qt] + bq4);
            *reinterpret_cast<uint2*>(pl + qr * 64 + (cby ^ (((qr >> 1) & 3) << 4))) = pk;
        }
    }
    __syncthreads();                                     // barrier 1

    // ---- phase 2: attention, wave owns q-stripe [w*16, w*16+16) ----
    const int qrow = w * 16 + lr;
    const int qg = qblk * 64 + qrow;
    const int swzq = ((qrow >> 1) & 3) << 4;
    const unsigned short* kp[4];
#pragma unroll
    for (int nt = 0; nt < 4; ++nt) {
        int key = nt * 16 + lr;
        int kr = (wi * 8 + (key >> 3) + 4) & 63;
        int kc = (wj * 8 + (key & 7) + 4) & 63;
        kp[nt] = Kb + ((size_t)(b * 4096 + kr * 64 + kc)) * 256 + lg * 8;
    }
    // V base: rolled layout, window rows never wrap
    const unsigned short* vgb = Vg + ((size_t)b << 20) + (wi * 8) * 64 + wj * 8
                                + (size_t)lr * 4096 + lg * 64;
    const float* bb = biasb + (size_t)qg * 64 + lg * 4;
    const u64* mrow = maskp + (size_t)win * 256 + qg;

#pragma unroll
    for (int h = 0; h < 8; ++h) {
        short8v qf = *reinterpret_cast<const short8v*>(
            L + h * 4096 + qrow * 64 + ((lg << 4) ^ swzq));
        f32x4 s[4];
        __builtin_amdgcn_s_setprio(1);
#pragma unroll
        for (int nt = 0; nt < 4; ++nt) {
            short8v kf = *reinterpret_cast<const short8v*>(kp[nt] + h * 32);
            f32x4 z = {0.f, 0.f, 0.f, 0.f};
            s[nt] = __builtin_amdgcn_mfma_f32_16x16x32_bf16(kf, qf, z, 0, 0, 0);
        }
        __builtin_amdgcn_s_setprio(0);
        // V fragments: direct global, independent of softmax -> issue early
        short8v vf[2][2];
#pragma unroll
        for (int kcp = 0; kcp < 2; ++kcp)
#pragma unroll
            for (int nt2 = 0; nt2 < 2; ++nt2)
                vf[kcp][nt2] = *reinterpret_cast<const short8v*>(
                    vgb + (size_t)(h * 32 + nt2 * 16) * 4096 + (kcp * 4) * 64);

        u64 mb = mrow[(size_t)h * 16384];
        float vv[16];
        float m = -3.0e38f;
#pragma unroll
        for (int nt = 0; nt < 4; ++nt) {
            f32x4 b4 = *reinterpret_cast<const f32x4*>(bb + h * 16384 + nt * 16);
#pragma unroll
            for (int j = 0; j < 4; ++j) {
                float sv = s[nt][j] + b4[j];
                if ((mb >> (nt * 16 + lg * 4 + j)) & 1ull) sv = -1.0e9f;
                vv[nt * 4 + j] = sv;
                m = fmaxf(m, sv);
            }
        }
        m = fmaxf(m, __shfl_xor(m, 16, 64));
        m = fmaxf(m, __shfl_xor(m, 32, 64));
        float sum = 0.f;
#pragma unroll
        for (int i = 0; i < 16; ++i) { vv[i] = __expf(vv[i] - m); sum += vv[i]; }
        sum += __shfl_xor(sum, 16, 64);
        sum += __shfl_xor(sum, 32, 64);
        float inv = 1.0f / sum;
#pragma unroll
        for (int nt = 0; nt < 4; ++nt) {
            f32x4 pv = { vv[nt * 4 + 0] * inv, vv[nt * 4 + 1] * inv,
                         vv[nt * 4 + 2] * inv, vv[nt * 4 + 3] * inv };
            uint2 pk = pack4(pv);
            *reinterpret_cast<uint2*>(
                L + 32768 + (nt >> 1) * 4096 + qrow * 64 +
                ((((nt & 1) * 32 + lg * 8)) ^ swzq)) = pk;
        }
        // O_h = P V_h
        f32x4 o0 = {0.f, 0.f, 0.f, 0.f}, o1 = {0.f, 0.f, 0.f, 0.f};
        __builtin_amdgcn_s_setprio(1);
#pragma unroll
        for (int kcp = 0; kcp < 2; ++kcp) {
            short8v pf = *reinterpret_cast<const short8v*>(
                L + 32768 + kcp * 4096 + qrow * 64 + ((lg << 4) ^ swzq));
            o0 = __builtin_amdgcn_mfma_f32_16x16x32_bf16(vf[kcp][0], pf, o0, 0, 0, 0);
            o1 = __builtin_amdgcn_mfma_f32_16x16x32_bf16(vf[kcp][1], pf, o1, 0, 0, 0);
        }
        __builtin_amdgcn_s_setprio(0);
        // O slice -> Qs plane h (same-wave rows only)
        {
            uint2 pk0 = pack4(o0), pk1 = pack4(o1);
            *reinterpret_cast<uint2*>(
                L + h * 4096 + qrow * 64 + ((lg * 8) ^ swzq)) = pk0;
            *reinterpret_cast<uint2*>(
                L + h * 4096 + qrow * 64 + ((32 + lg * 8) ^ swzq)) = pk1;
        }
    }
    __syncthreads();                                     // barrier 2

    // ---- phase 3: out = O @ Wo + bo.  Wave owns n in [w*64, w*64+64) ----
#pragma unroll
    for (int i = 0; i < 16; ++i) acc[i] = {0.f, 0.f, 0.f, 0.f};
    const unsigned short* wob = WoT + (size_t)(w * 64 + lr) * 256 + lg * 8;
#pragma unroll
    for (int kt = 0; kt < 8; ++kt) {
        short8v wof[4], of[4];
#pragma unroll
        for (int nt = 0; nt < 4; ++nt)
            wof[nt] = *reinterpret_cast<const short8v*>(wob + nt * 4096 + kt * 32);
#pragma unroll
        for (int qt = 0; qt < 4; ++qt) {
            int qr = qt * 16 + lr;
            of[qt] = *reinterpret_cast<const short8v*>(
                L + kt * 4096 + qr * 64 + ((lg << 4) ^ (((qr >> 1) & 3) << 4)));
        }
        __builtin_amdgcn_s_setprio(1);
#pragma unroll
        for (int nt = 0; nt < 4; ++nt)
#pragma unroll
            for (int qt = 0; qt < 4; ++qt)
                acc[nt * 4 + qt] = __builtin_amdgcn_mfma_f32_16x16x32_bf16(
                    wof[nt], of[qt], acc[nt * 4 + qt], 0, 0, 0);
        __builtin_amdgcn_s_setprio(0);
    }
#pragma unroll
    for (int nt = 0; nt < 4; ++nt) {
        int n0 = w * 64 + nt * 16 + lg * 4;
        f32x4 bo4 = *reinterpret_cast<const f32x4*>(bo + n0);
#pragma unroll
        for (int qt = 0; qt < 4; ++qt) {
            int gr = (wi * 16 + qblk * 4 + qt + 8) & 127;
            int gc = (wj * 16 + lr + 8) & 127;
            f32x4 v = acc[nt * 4 + qt] + bo4;
            *reinterpret_cast<f32x4*>(
                out + ((size_t)((b * 128 + gr) * 128 + gc)) * 256 + n0) = v;
        }
    }
}

// ---------------------------------------------------------------------------
extern "C" void kernel_launch(void* const* d_in, const int* in_sizes, int n_in,
                              void* d_out, int out_size, void* d_ws, size_t ws_size,
                              hipStream_t stream) {
    const float* x    = (const float*)d_in[0];
    const float* z    = (const float*)d_in[1];
    const int*   mask = (const int*)d_in[2];
    const float* Wq   = (const float*)d_in[3];
    const float* bq   = (const float*)d_in[4];
    const float* Wkv  = (const float*)d_in[5];
    const float* bkv  = (const float*)d_in[6];
    const float* Wo   = (const float*)d_in[7];
    const float* bo   = (const float*)d_in[8];
    const float* rel  = (const float*)d_in[9];
    float* out = (float*)d_out;

    // workspace layout (~35.7 MB)
    char* ws = (char*)d_ws;
    unsigned short* Kb    = (unsigned short*)(ws);                 // 16,777,216 B
    unsigned short* Vg    = (unsigned short*)(ws + 16777216);      // 16,777,216 B
    unsigned short* WqT   = (unsigned short*)(ws + 33554432);      //    131,072 B
    unsigned short* WkvT  = (unsigned short*)(ws + 33685504);      //    262,144 B
    unsigned short* WoT   = (unsigned short*)(ws + 33947648);      //    131,072 B
    float*          biasb = (float*)(ws + 34078720);               //    524,288 B
    u64*            maskp = (u64*)(ws + 34603008);                 //  1,048,576 B
    float*          bqs   = (float*)(ws + 35651584);               //      1,024 B

    prep_weights<<<1024, 256, 0, stream>>>(Wq, Wkv, Wo, WqT, WkvT, WoT);
    prep_bias<<<513, 256, 0, stream>>>(rel, bq, biasb, bqs);
    prep_mask<<<512, 256, 0, stream>>>(mask, maskp);

    // KV = z @ Wkv + bkv: K -> Kb [sp][256], V -> Vg transposed+rolled
    gemm_kv<<<dim3(4, 256), 256, 0, stream>>>(z, WkvT, bkv, Kb, Vg, 256);

    // fused Q-proj + window attention + O-proj
    fused_attn<<<dim3(4, 64, 8), 256, 0, stream>>>(
        x, Kb, Vg, WqT, WoT, bqs, bo, maskp, biasb, out);
}

// Round 8
// 284.564 us; speedup vs baseline: 1.0531x; 1.0531x over previous
//
#include <hip/hip_runtime.h>
#include <hip/hip_bf16.h>
#include <type_traits>

// ---------------------------------------------------------------------------
// Problem constants
//   x: (8,128,128,256) f32   z: (8,64,64,256) f32   mask: (1,8,8,8,256,64) int
//   Wq (256,256) bq(256)  Wkv (256,512) bkv(512)  Wo (256,256) bo(256)
//   rel_table (900,8) f32   out: (8,128,128,256) f32
// ---------------------------------------------------------------------------

typedef __attribute__((ext_vector_type(8))) short short8v;     // MFMA bf16 frag
typedef __attribute__((ext_vector_type(4))) float f32x4;       // MFMA acc
typedef __attribute__((ext_vector_type(8))) unsigned short ushort8v;
typedef unsigned long long u64;

#define DEV __device__ __forceinline__

DEV unsigned short f2bf(float f) {               // round-to-nearest-even f32->bf16
    union { float f; unsigned u; } v; v.f = f;
    unsigned r = v.u + 0x7FFFu + ((v.u >> 16) & 1u);
    return (unsigned short)(r >> 16);
}

DEV short8v cvt_f32x8(const float4 lo, const float4 hi) {      // 8 f32 -> 8 bf16
    union U { __hip_bfloat162 h[4]; short8v s; } u;
    u.h[0] = __float22bfloat162_rn(float2{lo.x, lo.y});
    u.h[1] = __float22bfloat162_rn(float2{lo.z, lo.w});
    u.h[2] = __float22bfloat162_rn(float2{hi.x, hi.y});
    u.h[3] = __float22bfloat162_rn(float2{hi.z, hi.w});
    return u.s;
}

DEV uint2 pack4(f32x4 v) {                       // 4 f32 -> 4 bf16 (8 B)
    union { __hip_bfloat162 h; unsigned u; } a, b;
    a.h = __float22bfloat162_rn(float2{v[0], v[1]});
    b.h = __float22bfloat162_rn(float2{v[2], v[3]});
    return uint2{a.u, b.u};
}

#define ATT_SCALE 0.17677669529663687f           // 1/sqrt(32)

// ---------------------------------------------------------------------------
// Prep kernels
// ---------------------------------------------------------------------------
__global__ void prep_weights(const float* __restrict__ Wq, const float* __restrict__ Wkv,
                             const float* __restrict__ Wo,
                             unsigned short* __restrict__ WqT, unsigned short* __restrict__ WkvT,
                             unsigned short* __restrict__ WoT) {
    int idx = blockIdx.x * 256 + threadIdx.x;            // 262144 total
    if (idx < 65536) {
        int n = idx >> 8, k = idx & 255;
        WqT[idx] = f2bf(Wq[k * 256 + n] * ATT_SCALE);
    } else if (idx < 196608) {
        int i = idx - 65536;
        int n = i >> 8, k = i & 255;
        WkvT[i] = f2bf(Wkv[k * 512 + n]);
    } else {
        int i = idx - 196608;
        int n = i >> 8, k = i & 255;
        WoT[i] = f2bf(Wo[k * 256 + n]);
    }
}

__global__ void prep_bias(const float* __restrict__ rel_table, const float* __restrict__ bq,
                          float* __restrict__ biasb, float* __restrict__ bqs) {
    int idx = blockIdx.x * 256 + threadIdx.x;
    if (idx < 131072) {
        int head = idx >> 14;
        int q = (idx >> 6) & 255;
        int k = idx & 63;
        int qi = q >> 4, qj = q & 15;
        int ki = k >> 3, kj = k & 7;
        int r0 = qi - 2 * ki + 14, r1 = qj - 2 * kj + 14;
        biasb[idx] = rel_table[(r0 * 30 + r1) * 8 + head];
    } else if (idx < 131328) {
        int i = idx - 131072;
        bqs[i] = bq[i] * ATT_SCALE;
    }
}

__global__ void prep_mask(const int* __restrict__ mask, u64* __restrict__ mp) {
    int idx = blockIdx.x * 256 + threadIdx.x;            // 131072 rows
    const int4* src = reinterpret_cast<const int4*>(mask + (size_t)idx * 64);
    u64 bits = 0;
#pragma unroll
    for (int c = 0; c < 16; ++c) {
        int4 v = src[c];
        if (v.x) bits |= 1ull << (c * 4 + 0);
        if (v.y) bits |= 1ull << (c * 4 + 1);
        if (v.z) bits |= 1ull << (c * 4 + 2);
        if (v.w) bits |= 1ull << (c * 4 + 3);
    }
    mp[idx] = bits;
}

// ---------------------------------------------------------------------------
// KV-proj GEMM. K -> Kb [b*4096+sp][256] bf16 (un-rolled spatial).
// V -> Vg2 [b][win][d=256][key=64] bf16, window-major + pre-rolled:
//   key (p,q) rolled: p=(kr-4)&63, q=(kc-4)&63; win=(p>>3)*8+(q>>3);
//   key-in-window = (p&7)*8+(q&7).
// Fused attention then reads V^T fragments fully coalesced (64B lines).
// ---------------------------------------------------------------------------
__global__ __launch_bounds__(256) void gemm_kv(
    const float* __restrict__ Af, const unsigned short* __restrict__ BT,
    const float* __restrict__ bias, unsigned short* __restrict__ Kb,
    unsigned short* __restrict__ Vg2, int K)
{
    __shared__ __align__(16) unsigned char As[2][8192];   // 128 rows x 64B
    __shared__ __align__(16) unsigned char Bs[2][8192];

    const int tid = threadIdx.x;
    const int mb = blockIdx.y * 128, nb = blockIdx.x * 128;
    const int w = tid >> 6, lane = tid & 63, lr = lane & 15, lg = lane >> 4;
    const int wm = (w >> 1) * 64, wn = (w & 1) * 64;

    const int cr0 = (w << 5) + (lane >> 2);
    const int csp = lane & 3;
    const int cs0 = csp ^ ((cr0 >> 1) & 3);
    const int cs1 = csp ^ (((cr0 + 16) >> 1) & 3);

    auto stageB = [&](int buf, int kb) {
        __builtin_amdgcn_global_load_lds(
            (const __attribute__((address_space(1))) void*)(BT + (size_t)(nb + cr0) * K + kb + cs0 * 8),
            (__attribute__((address_space(3))) void*)(&Bs[buf][w << 11]), 16, 0, 0);
        __builtin_amdgcn_global_load_lds(
            (const __attribute__((address_space(1))) void*)(BT + (size_t)(nb + cr0 + 16) * K + kb + cs1 * 8),
            (__attribute__((address_space(3))) void*)(&Bs[buf][(w << 11) + 1024]), 16, 0, 0);
    };

    float4 areg[2][2];
    auto loadA = [&](int kb) {
#pragma unroll
        for (int i = 0; i < 2; ++i) {
            int flat = tid + (i << 8);
            int r = flat >> 2, sp = flat & 3;
            int s = sp ^ ((r >> 1) & 3);
            const float* src = Af + (size_t)(mb + r) * K + kb + s * 8;
            areg[i][0] = *reinterpret_cast<const float4*>(src);
            areg[i][1] = *reinterpret_cast<const float4*>(src + 4);
        }
    };
    auto writeA = [&](int buf) {
#pragma unroll
        for (int i = 0; i < 2; ++i) {
            int flat = tid + (i << 8);
            int r = flat >> 2, sp = flat & 3;
            ushort8v u = { f2bf(areg[i][0].x), f2bf(areg[i][0].y),
                           f2bf(areg[i][0].z), f2bf(areg[i][0].w),
                           f2bf(areg[i][1].x), f2bf(areg[i][1].y),
                           f2bf(areg[i][1].z), f2bf(areg[i][1].w) };
            *reinterpret_cast<ushort8v*>(&As[buf][r * 64 + sp * 16]) = u;
        }
    };
    auto rdA = [&](int buf, int row) -> short8v {
        int swz = (lg ^ ((row >> 1) & 3)) << 4;
        return *reinterpret_cast<const short8v*>(&As[buf][row * 64 + swz]);
    };
    auto rdB = [&](int buf, int row) -> short8v {
        int swz = (lg ^ ((row >> 1) & 3)) << 4;
        return *reinterpret_cast<const short8v*>(&Bs[buf][row * 64 + swz]);
    };

    f32x4 acc[4][4];
#pragma unroll
    for (int i = 0; i < 4; ++i)
#pragma unroll
        for (int j = 0; j < 4; ++j) acc[i][j] = {0.f, 0.f, 0.f, 0.f};

    loadA(0); stageB(0, 0); writeA(0);
    __syncthreads();

    const int NT = K >> 5;
    int cur = 0;
    for (int t = 0; t < NT; ++t) {
        if (t + 1 < NT) { loadA((t + 1) << 5); stageB(cur ^ 1, (t + 1) << 5); }
        short8v af[4], bfr[4];
#pragma unroll
        for (int mt = 0; mt < 4; ++mt) af[mt] = rdA(cur, wm + mt * 16 + lr);
#pragma unroll
        for (int nt = 0; nt < 4; ++nt) bfr[nt] = rdB(cur, wn + nt * 16 + lr);
#pragma unroll
        for (int mt = 0; mt < 4; ++mt)
#pragma unroll
            for (int nt = 0; nt < 4; ++nt)
                acc[mt][nt] = __builtin_amdgcn_mfma_f32_16x16x32_bf16(
                    af[mt], bfr[nt], acc[mt][nt], 0, 0, 0);
        if (t + 1 < NT) writeA(cur ^ 1);
        __syncthreads();
        cur ^= 1;
    }

#pragma unroll
    for (int mt = 0; mt < 4; ++mt) {
        int row0 = mb + wm + mt * 16 + lg * 4;
        int bb_ = row0 >> 12;
        int kr  = (row0 >> 6) & 63;
        int kc0 = row0 & 63;                      // 4-aligned
        int p   = (kr - 4) & 63;
        int q0  = (kc0 - 4) & 63;                 // 4-aligned -> same 8-run for j=0..3
        int win = (p >> 3) * 8 + (q0 >> 3);
        int key0 = (p & 7) * 8 + (q0 & 7);
#pragma unroll
        for (int nt = 0; nt < 4; ++nt) {
            int col = nb + wn + nt * 16 + lr;
            f32x4 v;
#pragma unroll
            for (int j = 0; j < 4; ++j) v[j] = acc[mt][nt][j] + bias[col];
            if (col < 256) {                      // uniform per block
#pragma unroll
                for (int j = 0; j < 4; ++j)
                    Kb[(size_t)(row0 + j) * 256 + col] = f2bf(v[j]);
            } else {
                uint2 pk = pack4(v);
                *reinterpret_cast<uint2*>(
                    Vg2 + (((size_t)(bb_ * 64 + win) * 256 + (col - 256)) << 6) + key0) = pk;
            }
        }
    }
}

// ---------------------------------------------------------------------------
// Mega-fused kernel v3: Q-proj + 8-head window attention + O-proj.
// Block = (qblk 0..3, win 0..63, b 0..7), 256 thr / 4 waves; 64 q rows.
// LDS 40KB: Qs/Os 8 planes x [64q][64B] = 32KB (O_h overwrites Q plane h
// after head h consumes it) + Ps 2 planes = 8KB  -> 4 blocks/CU (LDS-bound).
// V^T read DIRECT from window-major Vg2 (coalesced 64B lines). K direct from
// Kb. W panels direct from L2. 2 barriers total. No forced occupancy bound.
// ---------------------------------------------------------------------------
__global__ __launch_bounds__(256) void fused_attn(
    const float* __restrict__ x, const unsigned short* __restrict__ Kb,
    const unsigned short* __restrict__ Vg2,
    const unsigned short* __restrict__ WqT, const unsigned short* __restrict__ WoT,
    const float* __restrict__ bqs, const float* __restrict__ bo,
    const u64* __restrict__ maskp, const float* __restrict__ biasb,
    float* __restrict__ out)
{
    __shared__ __align__(16) unsigned char L[40960];
    // Qs/Os: L + kt*4096          kt = 0..7   [64 q][64 B]
    // Ps:    L + 32768 + kc*4096  kc = 0..1   [64 q][64 B]

    const int tid = threadIdx.x;
    const int w = tid >> 6, lane = tid & 63, lr = lane & 15, lg = lane >> 4;
    const int qblk = blockIdx.x, win = blockIdx.y, b = blockIdx.z;
    const int wi = win >> 3, wj = win & 7;

    // ---- phase 1: Q = x @ Wq(scaled) + bq.  Wave owns n in [w*64, w*64+64) --
    f32x4 acc[16];
#pragma unroll
    for (int i = 0; i < 16; ++i) acc[i] = {0.f, 0.f, 0.f, 0.f};

    const unsigned short* wqb = WqT + (size_t)(w * 64 + lr) * 256 + lg * 8;
    const float* xr[4];
#pragma unroll
    for (int qt = 0; qt < 4; ++qt) {
        int gr = (wi * 16 + qblk * 4 + qt + 8) & 127;
        int gc = (wj * 16 + lr + 8) & 127;
        xr[qt] = x + ((size_t)((b * 128 + gr) * 128 + gc)) * 256 + lg * 8;
    }
#pragma unroll
    for (int kt = 0; kt < 8; ++kt) {
        short8v wqf[4], xf[4];
#pragma unroll
        for (int nt = 0; nt < 4; ++nt)
            wqf[nt] = *reinterpret_cast<const short8v*>(wqb + nt * 4096 + kt * 32);
#pragma unroll
        for (int qt = 0; qt < 4; ++qt) {
            float4 lo = *reinterpret_cast<const float4*>(xr[qt] + kt * 32);
            float4 hi = *reinterpret_cast<const float4*>(xr[qt] + kt * 32 + 4);
            xf[qt] = cvt_f32x8(lo, hi);
        }
        __builtin_amdgcn_s_setprio(1);
#pragma unroll
        for (int nt = 0; nt < 4; ++nt)
#pragma unroll
            for (int qt = 0; qt < 4; ++qt)
                acc[nt * 4 + qt] = __builtin_amdgcn_mfma_f32_16x16x32_bf16(
                    wqf[nt], xf[qt], acc[nt * 4 + qt], 0, 0, 0);
        __builtin_amdgcn_s_setprio(0);
    }
#pragma unroll
    for (int nt = 0; nt < 4; ++nt) {
        int n0 = w * 64 + nt * 16 + lg * 4;
        f32x4 bq4 = *reinterpret_cast<const f32x4*>(bqs + n0);
        unsigned char* pl = L + (w * 2 + (nt >> 1)) * 4096;
        int cby = (nt & 1) * 32 + lg * 8;
#pragma unroll
        for (int qt = 0; qt < 4; ++qt) {
            int qr = qt * 16 + lr;
            uint2 pk = pack4(acc[nt * 4 + qt] + bq4);
            *reinterpret_cast<uint2*>(pl + qr * 64 + (cby ^ (((qr >> 1) & 3) << 4))) = pk;
        }
    }
    __syncthreads();                                     // barrier 1

    // ---- phase 2: attention, wave owns q-stripe [w*16, w*16+16) ----
    const int qrow = w * 16 + lr;
    const int qg = qblk * 64 + qrow;
    const int swzq = ((qrow >> 1) & 3) << 4;
    const unsigned short* kp[4];
#pragma unroll
    for (int nt = 0; nt < 4; ++nt) {
        int key = nt * 16 + lr;
        int kr = (wi * 8 + (key >> 3) + 4) & 63;
        int kc = (wj * 8 + (key & 7) + 4) & 63;
        kp[nt] = Kb + ((size_t)(b * 4096 + kr * 64 + kc)) * 256 + lg * 8;
    }
    // V^T base (window-major, pre-rolled): lane reads d=...+lr, key=kcp*32+lg*8
    const unsigned short* vgb = Vg2 + (((size_t)(b * 64 + win) * 256 + lr) << 6) + lg * 8;
    const float* bb = biasb + (size_t)qg * 64 + lg * 4;
    const u64* mrow = maskp + (size_t)win * 256 + qg;

#pragma unroll
    for (int h = 0; h < 8; ++h) {
        short8v qf = *reinterpret_cast<const short8v*>(
            L + h * 4096 + qrow * 64 + ((lg << 4) ^ swzq));
        f32x4 s[4];
        __builtin_amdgcn_s_setprio(1);
#pragma unroll
        for (int nt = 0; nt < 4; ++nt) {
            short8v kf = *reinterpret_cast<const short8v*>(kp[nt] + h * 32);
            f32x4 z = {0.f, 0.f, 0.f, 0.f};
            s[nt] = __builtin_amdgcn_mfma_f32_16x16x32_bf16(kf, qf, z, 0, 0, 0);
        }
        __builtin_amdgcn_s_setprio(0);
        // V^T fragments: coalesced direct global, independent of softmax
        short8v vf[2][2];
#pragma unroll
        for (int kcp = 0; kcp < 2; ++kcp)
#pragma unroll
            for (int nt2 = 0; nt2 < 2; ++nt2)
                vf[kcp][nt2] = *reinterpret_cast<const short8v*>(
                    vgb + ((size_t)(h * 32 + nt2 * 16) << 6) + kcp * 32);

        u64 mb = mrow[(size_t)h * 16384];
        float vv[16];
        float m = -3.0e38f;
#pragma unroll
        for (int nt = 0; nt < 4; ++nt) {
            f32x4 b4 = *reinterpret_cast<const f32x4*>(bb + h * 16384 + nt * 16);
#pragma unroll
            for (int j = 0; j < 4; ++j) {
                float sv = s[nt][j] + b4[j];
                if ((mb >> (nt * 16 + lg * 4 + j)) & 1ull) sv = -1.0e9f;
                vv[nt * 4 + j] = sv;
                m = fmaxf(m, sv);
            }
        }
        m = fmaxf(m, __shfl_xor(m, 16, 64));
        m = fmaxf(m, __shfl_xor(m, 32, 64));
        float sum = 0.f;
#pragma unroll
        for (int i = 0; i < 16; ++i) { vv[i] = __expf(vv[i] - m); sum += vv[i]; }
        sum += __shfl_xor(sum, 16, 64);
        sum += __shfl_xor(sum, 32, 64);
        float inv = 1.0f / sum;
#pragma unroll
        for (int nt = 0; nt < 4; ++nt) {
            f32x4 pv = { vv[nt * 4 + 0] * inv, vv[nt * 4 + 1] * inv,
                         vv[nt * 4 + 2] * inv, vv[nt * 4 + 3] * inv };
            uint2 pk = pack4(pv);
            *reinterpret_cast<uint2*>(
                L + 32768 + (nt >> 1) * 4096 + qrow * 64 +
                ((((nt & 1) * 32 + lg * 8)) ^ swzq)) = pk;
        }
        // O_h = P V_h
        f32x4 o0 = {0.f, 0.f, 0.f, 0.f}, o1 = {0.f, 0.f, 0.f, 0.f};
        __builtin_amdgcn_s_setprio(1);
#pragma unroll
        for (int kcp = 0; kcp < 2; ++kcp) {
            short8v pf = *reinterpret_cast<const short8v*>(
                L + 32768 + kcp * 4096 + qrow * 64 + ((lg << 4) ^ swzq));
            o0 = __builtin_amdgcn_mfma_f32_16x16x32_bf16(vf[kcp][0], pf, o0, 0, 0, 0);
            o1 = __builtin_amdgcn_mfma_f32_16x16x32_bf16(vf[kcp][1], pf, o1, 0, 0, 0);
        }
        __builtin_amdgcn_s_setprio(0);
        // O slice -> Qs plane h (same-wave rows only)
        {
            uint2 pk0 = pack4(o0), pk1 = pack4(o1);
            *reinterpret_cast<uint2*>(
                L + h * 4096 + qrow * 64 + ((lg * 8) ^ swzq)) = pk0;
            *reinterpret_cast<uint2*>(
                L + h * 4096 + qrow * 64 + ((32 + lg * 8) ^ swzq)) = pk1;
        }
    }
    __syncthreads();                                     // barrier 2

    // ---- phase 3: out = O @ Wo + bo.  Wave owns n in [w*64, w*64+64) ----
#pragma unroll
    for (int i = 0; i < 16; ++i) acc[i] = {0.f, 0.f, 0.f, 0.f};
    const unsigned short* wob = WoT + (size_t)(w * 64 + lr) * 256 + lg * 8;
#pragma unroll
    for (int kt = 0; kt < 8; ++kt) {
        short8v wof[4], of[4];
#pragma unroll
        for (int nt = 0; nt < 4; ++nt)
            wof[nt] = *reinterpret_cast<const short8v*>(wob + nt * 4096 + kt * 32);
#pragma unroll
        for (int qt = 0; qt < 4; ++qt) {
            int qr = qt * 16 + lr;
            of[qt] = *reinterpret_cast<const short8v*>(
                L + kt * 4096 + qr * 64 + ((lg << 4) ^ (((qr >> 1) & 3) << 4)));
        }
        __builtin_amdgcn_s_setprio(1);
#pragma unroll
        for (int nt = 0; nt < 4; ++nt)
#pragma unroll
            for (int qt = 0; qt < 4; ++qt)
                acc[nt * 4 + qt] = __builtin_amdgcn_mfma_f32_16x16x32_bf16(
                    wof[nt], of[qt], acc[nt * 4 + qt], 0, 0, 0);
        __builtin_amdgcn_s_setprio(0);
    }
#pragma unroll
    for (int nt = 0; nt < 4; ++nt) {
        int n0 = w * 64 + nt * 16 + lg * 4;
        f32x4 bo4 = *reinterpret_cast<const f32x4*>(bo + n0);
#pragma unroll
        for (int qt = 0; qt < 4; ++qt) {
            int gr = (wi * 16 + qblk * 4 + qt + 8) & 127;
            int gc = (wj * 16 + lr + 8) & 127;
            f32x4 v = acc[nt * 4 + qt] + bo4;
            *reinterpret_cast<f32x4*>(
                out + ((size_t)((b * 128 + gr) * 128 + gc)) * 256 + n0) = v;
        }
    }
}

// ---------------------------------------------------------------------------
extern "C" void kernel_launch(void* const* d_in, const int* in_sizes, int n_in,
                              void* d_out, int out_size, void* d_ws, size_t ws_size,
                              hipStream_t stream) {
    const float* x    = (const float*)d_in[0];
    const float* z    = (const float*)d_in[1];
    const int*   mask = (const int*)d_in[2];
    const float* Wq   = (const float*)d_in[3];
    const float* bq   = (const float*)d_in[4];
    const float* Wkv  = (const float*)d_in[5];
    const float* bkv  = (const float*)d_in[6];
    const float* Wo   = (const float*)d_in[7];
    const float* bo   = (const float*)d_in[8];
    const float* rel  = (const float*)d_in[9];
    float* out = (float*)d_out;

    // workspace layout (~35.7 MB)
    char* ws = (char*)d_ws;
    unsigned short* Kb    = (unsigned short*)(ws);                 // 16,777,216 B
    unsigned short* Vg2   = (unsigned short*)(ws + 16777216);      // 16,777,216 B
    unsigned short* WqT   = (unsigned short*)(ws + 33554432);      //    131,072 B
    unsigned short* WkvT  = (unsigned short*)(ws + 33685504);      //    262,144 B
    unsigned short* WoT   = (unsigned short*)(ws + 33947648);      //    131,072 B
    float*          biasb = (float*)(ws + 34078720);               //    524,288 B
    u64*            maskp = (u64*)(ws + 34603008);                 //  1,048,576 B
    float*          bqs   = (float*)(ws + 35651584);               //      1,024 B

    prep_weights<<<1024, 256, 0, stream>>>(Wq, Wkv, Wo, WqT, WkvT, WoT);
    prep_bias<<<513, 256, 0, stream>>>(rel, bq, biasb, bqs);
    prep_mask<<<512, 256, 0, stream>>>(mask, maskp);

    // KV = z @ Wkv + bkv: K -> Kb [sp][256], V -> Vg2 window-major transposed
    gemm_kv<<<dim3(4, 256), 256, 0, stream>>>(z, WkvT, bkv, Kb, Vg2, 256);

    // fused Q-proj + window attention + O-proj
    fused_attn<<<dim3(4, 64, 8), 256, 0, stream>>>(
        x, Kb, Vg2, WqT, WoT, bqs, bo, maskp, biasb, out);
}

// Round 9
// 219.549 us; speedup vs baseline: 1.3650x; 1.2961x over previous
//
#include <hip/hip_runtime.h>
#include <hip/hip_bf16.h>
#include <type_traits>

// ---------------------------------------------------------------------------
// Problem constants
//   x: (8,128,128,256) f32   z: (8,64,64,256) f32   mask: (1,8,8,8,256,64) int
//   Wq (256,256) bq(256)  Wkv (256,512) bkv(512)  Wo (256,256) bo(256)
//   rel_table (900,8) f32   out: (8,128,128,256) f32
// ---------------------------------------------------------------------------

typedef __attribute__((ext_vector_type(8))) short short8v;     // MFMA bf16 frag
typedef __attribute__((ext_vector_type(4))) float f32x4;       // MFMA acc
typedef __attribute__((ext_vector_type(8))) unsigned short ushort8v;
typedef __attribute__((ext_vector_type(4))) unsigned short ushort4v;
typedef unsigned long long u64;

#define DEV __device__ __forceinline__

DEV unsigned short f2bf(float f) {               // round-to-nearest-even f32->bf16
    union { float f; unsigned u; } v; v.f = f;
    unsigned r = v.u + 0x7FFFu + ((v.u >> 16) & 1u);
    return (unsigned short)(r >> 16);
}

DEV short8v cvt_f32x8(const float4 lo, const float4 hi) {      // 8 f32 -> 8 bf16
    union U { __hip_bfloat162 h[4]; short8v s; } u;
    u.h[0] = __float22bfloat162_rn(float2{lo.x, lo.y});
    u.h[1] = __float22bfloat162_rn(float2{lo.z, lo.w});
    u.h[2] = __float22bfloat162_rn(float2{hi.x, hi.y});
    u.h[3] = __float22bfloat162_rn(float2{hi.z, hi.w});
    return u.s;
}

#define ATT_SCALE 0.17677669529663687f           // 1/sqrt(32)

// ---------------------------------------------------------------------------
// Prep kernels (R2-proven)
// ---------------------------------------------------------------------------
__global__ void prep_weights(const float* __restrict__ Wq, const float* __restrict__ Wkv,
                             const float* __restrict__ Wo,
                             unsigned short* __restrict__ WqT, unsigned short* __restrict__ WkvT,
                             unsigned short* __restrict__ WoT) {
    int idx = blockIdx.x * 256 + threadIdx.x;            // 262144 total
    if (idx < 65536) {
        int n = idx >> 8, k = idx & 255;
        WqT[idx] = f2bf(Wq[k * 256 + n] * ATT_SCALE);
    } else if (idx < 196608) {
        int i = idx - 65536;
        int n = i >> 8, k = i & 255;
        WkvT[i] = f2bf(Wkv[k * 512 + n]);
    } else {
        int i = idx - 196608;
        int n = i >> 8, k = i & 255;
        WoT[i] = f2bf(Wo[k * 256 + n]);
    }
}

__global__ void prep_bias(const float* __restrict__ rel_table, const float* __restrict__ bq,
                          float* __restrict__ biasb, float* __restrict__ bqs) {
    int idx = blockIdx.x * 256 + threadIdx.x;
    if (idx < 131072) {
        int head = idx >> 14;
        int q = (idx >> 6) & 255;
        int k = idx & 63;
        int qi = q >> 4, qj = q & 15;
        int ki = k >> 3, kj = k & 7;
        int r0 = qi - 2 * ki + 14, r1 = qj - 2 * kj + 14;
        biasb[idx] = rel_table[(r0 * 30 + r1) * 8 + head];
    } else if (idx < 131328) {
        int i = idx - 131072;
        bqs[i] = bq[i] * ATT_SCALE;
    }
}

__global__ void prep_mask(const int* __restrict__ mask, u64* __restrict__ mp) {
    int idx = blockIdx.x * 256 + threadIdx.x;            // 131072 rows
    const int4* src = reinterpret_cast<const int4*>(mask + (size_t)idx * 64);
    u64 bits = 0;
#pragma unroll
    for (int c = 0; c < 16; ++c) {
        int4 v = src[c];
        if (v.x) bits |= 1ull << (c * 4 + 0);
        if (v.y) bits |= 1ull << (c * 4 + 1);
        if (v.z) bits |= 1ull << (c * 4 + 2);
        if (v.w) bits |= 1ull << (c * 4 + 3);
    }
    mp[idx] = bits;
}

// ---------------------------------------------------------------------------
// Weight-stationary streaming GEMM: C[M][256] = A[M][256] * B + bias,
// B^T row-major bf16 [256][256] staged ENTIRELY in LDS (128 KB, kt-plane
// layout [8 kt][256 n][64 B] with the R3-proven 0-conflict slot-XOR).
// Block = 512 thr (8 waves), 1 block/CU, 512 rows/block, 64 rows/wave.
// After the single staging barrier the loop is barrier-free: each wave
// streams 16-row A tiles global->reg (2-tile-deep prefetch, 32 KB in
// flight/wave), cvt in-reg, 128 MFMA/tile, epilogue direct to global.
// ---------------------------------------------------------------------------
template <bool AF32, bool OUT_BF16>
__global__ __launch_bounds__(512) void gemm_ws(
    const void* __restrict__ Ain, const unsigned short* __restrict__ BT,
    const float* __restrict__ bias, void* __restrict__ Cout)
{
    __shared__ __align__(16) unsigned char Wl[131072];   // [8 kt][256 n][64 B]
    const float* Af = (const float*)Ain;
    const unsigned short* Ab = (const unsigned short*)Ain;

    const int tid = threadIdx.x;
    const int w = tid >> 6, lane = tid & 63, lr = lane & 15, lg = lane >> 4;
    const size_t wm = (size_t)blockIdx.x * 512 + w * 64;

    // ---- stage W once: 512 threads x 256 B ----
    {
        int r = tid >> 1, half = tid & 1;
        const unsigned short* src = BT + r * 256 + half * 128;
        int rsw = (r >> 1) & 3;
#pragma unroll
        for (int kk = 0; kk < 4; ++kk) {
            int kt = half * 4 + kk;
#pragma unroll
            for (int sl = 0; sl < 4; ++sl) {
                ushort8v v = *reinterpret_cast<const ushort8v*>(src + kk * 32 + sl * 8);
                *reinterpret_cast<ushort8v*>(
                    &Wl[kt * 16384 + r * 64 + ((sl ^ rsw) << 4)]) = v;
            }
        }
    }
    __syncthreads();                                     // the ONLY barrier

    const int swzb = (lg ^ ((lr >> 1) & 3)) << 4;        // lane-constant read swz

    float bcol[16];
#pragma unroll
    for (int nt = 0; nt < 16; ++nt) bcol[nt] = bias[nt * 16 + lr];

#define RD_W(kt, nt) (*reinterpret_cast<const short8v*>( \
        &Wl[(kt) * 16384 + ((nt) * 16 + lr) * 64 + swzb]))

#define EPILOGUE(t)                                                             \
    _Pragma("unroll")                                                           \
    for (int nt = 0; nt < 16; ++nt) {                                           \
        _Pragma("unroll")                                                       \
        for (int j = 0; j < 4; ++j) {                                           \
            size_t row = wm + (t) * 16 + lg * 4 + j;                            \
            int col = nt * 16 + lr;                                             \
            float v = acc[nt][j] + bcol[nt];                                    \
            if constexpr (OUT_BF16)                                             \
                ((unsigned short*)Cout)[row * 256 + col] = f2bf(v);             \
            else                                                                \
                ((float*)Cout)[row * 256 + col] = v;                            \
        }                                                                       \
    }

    if constexpr (AF32) {
        float4 bufA[16], bufB[16];
#define LOADT_F(BUF, t) {                                                       \
        const float* p = Af + (wm + (t) * 16 + lr) * 256 + lg * 8;              \
        _Pragma("unroll")                                                       \
        for (int kt = 0; kt < 8; ++kt) {                                        \
            BUF[kt * 2]     = *reinterpret_cast<const float4*>(p + kt * 32);    \
            BUF[kt * 2 + 1] = *reinterpret_cast<const float4*>(p + kt * 32 + 4);\
        } }
#define COMP_F(BUF, t) {                                                        \
        f32x4 acc[16];                                                          \
        _Pragma("unroll")                                                       \
        for (int nt = 0; nt < 16; ++nt) acc[nt] = {0.f, 0.f, 0.f, 0.f};         \
        _Pragma("unroll")                                                       \
        for (int kt = 0; kt < 8; ++kt) {                                        \
            short8v a = cvt_f32x8(BUF[kt * 2], BUF[kt * 2 + 1]);                \
            _Pragma("unroll")                                                   \
            for (int nt = 0; nt < 16; ++nt)                                     \
                acc[nt] = __builtin_amdgcn_mfma_f32_16x16x32_bf16(              \
                    a, RD_W(kt, nt), acc[nt], 0, 0, 0);                         \
        }                                                                       \
        EPILOGUE(t) }
        LOADT_F(bufA, 0);
        LOADT_F(bufB, 1); COMP_F(bufA, 0);
        LOADT_F(bufA, 2); COMP_F(bufB, 1);
        LOADT_F(bufB, 3); COMP_F(bufA, 2);
        COMP_F(bufB, 3);
#undef LOADT_F
#undef COMP_F
    } else {
        short8v bufA[8], bufB[8];
#define LOADT_B(BUF, t) {                                                       \
        const unsigned short* p = Ab + (wm + (t) * 16 + lr) * 256 + lg * 8;     \
        _Pragma("unroll")                                                       \
        for (int kt = 0; kt < 8; ++kt)                                          \
            BUF[kt] = *reinterpret_cast<const short8v*>(p + kt * 32); }
#define COMP_B(BUF, t) {                                                        \
        f32x4 acc[16];                                                          \
        _Pragma("unroll")                                                       \
        for (int nt = 0; nt < 16; ++nt) acc[nt] = {0.f, 0.f, 0.f, 0.f};         \
        _Pragma("unroll")                                                       \
        for (int kt = 0; kt < 8; ++kt) {                                        \
            _Pragma("unroll")                                                   \
            for (int nt = 0; nt < 16; ++nt)                                     \
                acc[nt] = __builtin_amdgcn_mfma_f32_16x16x32_bf16(              \
                    BUF[kt], RD_W(kt, nt), acc[nt], 0, 0, 0);                   \
        }                                                                       \
        EPILOGUE(t) }
        LOADT_B(bufA, 0);
        LOADT_B(bufB, 1); COMP_B(bufA, 0);
        LOADT_B(bufA, 2); COMP_B(bufB, 1);
        LOADT_B(bufB, 3); COMP_B(bufA, 2);
        COMP_B(bufB, 3);
#undef LOADT_B
#undef COMP_B
    }
#undef RD_W
#undef EPILOGUE
}

// ---------------------------------------------------------------------------
// KV-proj GEMM (R3-proven double-buffered gemm_proj, f32-A, bf16 out).
// ---------------------------------------------------------------------------
template <bool AF32, bool OUT_BF16>
__global__ __launch_bounds__(256) void gemm_proj(
    const void* __restrict__ Ain, const unsigned short* __restrict__ BT,
    const float* __restrict__ bias, void* __restrict__ Cout,
    int M, int N, int K)
{
    __shared__ __align__(16) unsigned char As[2][8192];
    __shared__ __align__(16) unsigned char Bs[2][8192];
    const float* Af = (const float*)Ain;

    const int tid = threadIdx.x;
    const int mb = blockIdx.y * 128, nb = blockIdx.x * 128;
    const int w = tid >> 6, lane = tid & 63, lr = lane & 15, lg = lane >> 4;
    const int wm = (w >> 1) * 64, wn = (w & 1) * 64;

    const int cr0 = (w << 5) + (lane >> 2);
    const int csp = lane & 3;
    const int cs0 = csp ^ ((cr0 >> 1) & 3);
    const int cs1 = csp ^ (((cr0 + 16) >> 1) & 3);

    auto stageB = [&](int buf, int kb) {
        __builtin_amdgcn_global_load_lds(
            (const __attribute__((address_space(1))) void*)(BT + (size_t)(nb + cr0) * K + kb + cs0 * 8),
            (__attribute__((address_space(3))) void*)(&Bs[buf][w << 11]), 16, 0, 0);
        __builtin_amdgcn_global_load_lds(
            (const __attribute__((address_space(1))) void*)(BT + (size_t)(nb + cr0 + 16) * K + kb + cs1 * 8),
            (__attribute__((address_space(3))) void*)(&Bs[buf][(w << 11) + 1024]), 16, 0, 0);
    };

    float4 areg[2][2];
    auto loadA = [&](int kb) {
#pragma unroll
        for (int i = 0; i < 2; ++i) {
            int flat = tid + (i << 8);
            int r = flat >> 2, sp = flat & 3;
            int s = sp ^ ((r >> 1) & 3);
            const float* src = Af + (size_t)(mb + r) * K + kb + s * 8;
            areg[i][0] = *reinterpret_cast<const float4*>(src);
            areg[i][1] = *reinterpret_cast<const float4*>(src + 4);
        }
    };
    auto writeA = [&](int buf) {
#pragma unroll
        for (int i = 0; i < 2; ++i) {
            int flat = tid + (i << 8);
            int r = flat >> 2, sp = flat & 3;
            ushort8v u = { f2bf(areg[i][0].x), f2bf(areg[i][0].y),
                           f2bf(areg[i][0].z), f2bf(areg[i][0].w),
                           f2bf(areg[i][1].x), f2bf(areg[i][1].y),
                           f2bf(areg[i][1].z), f2bf(areg[i][1].w) };
            *reinterpret_cast<ushort8v*>(&As[buf][r * 64 + sp * 16]) = u;
        }
    };
    auto rdA = [&](int buf, int row) -> short8v {
        int swz = (lg ^ ((row >> 1) & 3)) << 4;
        return *reinterpret_cast<const short8v*>(&As[buf][row * 64 + swz]);
    };
    auto rdB = [&](int buf, int row) -> short8v {
        int swz = (lg ^ ((row >> 1) & 3)) << 4;
        return *reinterpret_cast<const short8v*>(&Bs[buf][row * 64 + swz]);
    };

    f32x4 acc[4][4];
#pragma unroll
    for (int i = 0; i < 4; ++i)
#pragma unroll
        for (int j = 0; j < 4; ++j) acc[i][j] = {0.f, 0.f, 0.f, 0.f};

    loadA(0); stageB(0, 0); writeA(0);
    __syncthreads();

    const int NT = K >> 5;
    int cur = 0;
    for (int t = 0; t < NT; ++t) {
        if (t + 1 < NT) { loadA((t + 1) << 5); stageB(cur ^ 1, (t + 1) << 5); }
        short8v af[4], bfr[4];
#pragma unroll
        for (int mt = 0; mt < 4; ++mt) af[mt] = rdA(cur, wm + mt * 16 + lr);
#pragma unroll
        for (int nt = 0; nt < 4; ++nt) bfr[nt] = rdB(cur, wn + nt * 16 + lr);
#pragma unroll
        for (int mt = 0; mt < 4; ++mt)
#pragma unroll
            for (int nt = 0; nt < 4; ++nt)
                acc[mt][nt] = __builtin_amdgcn_mfma_f32_16x16x32_bf16(
                    af[mt], bfr[nt], acc[mt][nt], 0, 0, 0);
        if (t + 1 < NT) writeA(cur ^ 1);
        __syncthreads();
        cur ^= 1;
    }

#pragma unroll
    for (int mt = 0; mt < 4; ++mt)
#pragma unroll
        for (int nt = 0; nt < 4; ++nt)
#pragma unroll
            for (int j = 0; j < 4; ++j) {
                int row = mb + wm + mt * 16 + lg * 4 + j;
                int col = nb + wn + nt * 16 + lr;
                float v = acc[mt][nt][j] + bias[col];
                if constexpr (OUT_BF16)
                    ((unsigned short*)Cout)[(size_t)row * N + col] = f2bf(v);
                else
                    ((float*)Cout)[(size_t)row * N + col] = v;
            }
}

// ---------------------------------------------------------------------------
// Fused window attention (R1/R2-proven, verbatim).
// ---------------------------------------------------------------------------
__global__ __launch_bounds__(256) void win_attn(
    unsigned short* __restrict__ Qbuf,            // [8*128*128, 256] bf16 (in/out)
    const unsigned short* __restrict__ KVbuf,     // [8*64*64, 512] bf16
    const u64* __restrict__ maskp,                // [8][64][256] packed bits
    const float* __restrict__ biasb)              // [8][256][64]
{
    __shared__ __align__(16) unsigned char Pb[256 * 128];   // P, 64-wide XOR-swizzled
    __shared__ __align__(16) unsigned short Vt[32][72];     // V^T: [dk][key]

    const int tid = threadIdx.x;
    const int win = blockIdx.x, head = blockIdx.y, b = blockIdx.z;
    const int wi = win >> 3, wj = win & 7;
    const int w = tid >> 6, lane = tid & 63, lr = lane & 15, lg = lane >> 4;
    const int qb = w * 64;

    {
        int key = tid & 63, c = tid >> 6;
        int kr = (wi * 8 + (key >> 3) + 4) & 63;
        int kc = (wj * 8 + (key & 7) + 4) & 63;
        ushort8v v = *reinterpret_cast<const ushort8v*>(
            KVbuf + ((size_t)(b * 4096 + kr * 64 + kc)) * 512 + 256 + head * 32 + c * 8);
#pragma unroll
        for (int e = 0; e < 8; ++e) Vt[c * 8 + e][key] = v[e];
    }

    short8v qf[4], kf[4];
#pragma unroll
    for (int mt = 0; mt < 4; ++mt) {
        int q = qb + mt * 16 + lr;
        int gr = (wi * 16 + (q >> 4) + 8) & 127;
        int gc = (wj * 16 + (q & 15) + 8) & 127;
        qf[mt] = *reinterpret_cast<const short8v*>(
            Qbuf + ((size_t)(b * 16384 + gr * 128 + gc)) * 256 + head * 32 + lg * 8);
    }
#pragma unroll
    for (int nt = 0; nt < 4; ++nt) {
        int key = nt * 16 + lr;
        int kr = (wi * 8 + (key >> 3) + 4) & 63;
        int kc = (wj * 8 + (key & 7) + 4) & 63;
        kf[nt] = *reinterpret_cast<const short8v*>(
            KVbuf + ((size_t)(b * 4096 + kr * 64 + kc)) * 512 + head * 32 + lg * 8);
    }

    f32x4 s[4][4];
#pragma unroll
    for (int mt = 0; mt < 4; ++mt)
#pragma unroll
        for (int nt = 0; nt < 4; ++nt) s[mt][nt] = {0.f, 0.f, 0.f, 0.f};
    __builtin_amdgcn_s_setprio(1);
#pragma unroll
    for (int mt = 0; mt < 4; ++mt)
#pragma unroll
        for (int nt = 0; nt < 4; ++nt)
            s[mt][nt] = __builtin_amdgcn_mfma_f32_16x16x32_bf16(qf[mt], kf[nt], s[mt][nt], 0, 0, 0);
    __builtin_amdgcn_s_setprio(0);

    const u64* mrow = maskp + (size_t)(head * 64 + win) * 256;
#pragma unroll
    for (int mt = 0; mt < 4; ++mt) {
#pragma unroll
        for (int j = 0; j < 4; ++j) {
            int q = qb + mt * 16 + lg * 4 + j;
            u64 mb = mrow[q];
            const float* brow = biasb + (size_t)(head * 256 + q) * 64;
            float v[4];
            float m = -3.0e38f;
#pragma unroll
            for (int nt = 0; nt < 4; ++nt) {
                int key = nt * 16 + lr;
                float sv = s[mt][nt][j] + brow[key];
                if ((mb >> key) & 1ull) sv = -1.0e9f;
                v[nt] = sv;
                m = fmaxf(m, sv);
            }
#pragma unroll
            for (int d = 1; d < 16; d <<= 1) m = fmaxf(m, __shfl_xor(m, d, 64));
            float sum = 0.f;
#pragma unroll
            for (int nt = 0; nt < 4; ++nt) { v[nt] = __expf(v[nt] - m); sum += v[nt]; }
#pragma unroll
            for (int d = 1; d < 16; d <<= 1) sum += __shfl_xor(sum, d, 64);
            float inv = 1.0f / sum;
            int sw = (q & 7) << 4;
#pragma unroll
            for (int nt = 0; nt < 4; ++nt) {
                int off = q * 128 + (((nt * 16 + lr) * 2) ^ sw);
                *reinterpret_cast<unsigned short*>(Pb + off) = f2bf(v[nt] * inv);
            }
        }
    }

    __syncthreads();

    f32x4 o[4][2];
#pragma unroll
    for (int mt = 0; mt < 4; ++mt)
#pragma unroll
        for (int nt = 0; nt < 2; ++nt) o[mt][nt] = {0.f, 0.f, 0.f, 0.f};
#pragma unroll
    for (int kc = 0; kc < 2; ++kc) {
        short8v pf[4], vf[2];
#pragma unroll
        for (int mt = 0; mt < 4; ++mt) {
            int row = qb + mt * 16 + lr;
            int coff = (kc * 64 + lg * 16) ^ ((row & 7) << 4);
            pf[mt] = *reinterpret_cast<const short8v*>(Pb + row * 128 + coff);
        }
#pragma unroll
        for (int nt = 0; nt < 2; ++nt)
            vf[nt] = *reinterpret_cast<const short8v*>(&Vt[nt * 16 + lr][kc * 32 + lg * 8]);
        __builtin_amdgcn_s_setprio(1);
#pragma unroll
        for (int mt = 0; mt < 4; ++mt)
#pragma unroll
            for (int nt = 0; nt < 2; ++nt)
                o[mt][nt] = __builtin_amdgcn_mfma_f32_16x16x32_bf16(pf[mt], vf[nt], o[mt][nt], 0, 0, 0);
        __builtin_amdgcn_s_setprio(0);
    }

#pragma unroll
    for (int mt = 0; mt < 4; ++mt)
#pragma unroll
        for (int j = 0; j < 4; ++j) {
            int q = qb + mt * 16 + lg * 4 + j;
            int gr = (wi * 16 + (q >> 4) + 8) & 127;
            int gc = (wj * 16 + (q & 15) + 8) & 127;
            unsigned short* dst =
                Qbuf + ((size_t)(b * 16384 + gr * 128 + gc)) * 256 + head * 32;
#pragma unroll
            for (int nt = 0; nt < 2; ++nt)
                dst[nt * 16 + lr] = f2bf(o[mt][nt][j]);
        }
}

// ---------------------------------------------------------------------------
extern "C" void kernel_launch(void* const* d_in, const int* in_sizes, int n_in,
                              void* d_out, int out_size, void* d_ws, size_t ws_size,
                              hipStream_t stream) {
    const float* x    = (const float*)d_in[0];
    const float* z    = (const float*)d_in[1];
    const int*   mask = (const int*)d_in[2];
    const float* Wq   = (const float*)d_in[3];
    const float* bq   = (const float*)d_in[4];
    const float* Wkv  = (const float*)d_in[5];
    const float* bkv  = (const float*)d_in[6];
    const float* Wo   = (const float*)d_in[7];
    const float* bo   = (const float*)d_in[8];
    const float* rel  = (const float*)d_in[9];
    float* out = (float*)d_out;

    // workspace layout (~103 MB, R2-identical)
    char* ws = (char*)d_ws;
    unsigned short* Qbuf  = (unsigned short*)(ws);                 // 67,108,864 B
    unsigned short* KVbuf = (unsigned short*)(ws + 67108864);      // 33,554,432 B
    unsigned short* WqT   = (unsigned short*)(ws + 100663296);     //    131,072 B
    unsigned short* WkvT  = (unsigned short*)(ws + 100794368);     //    262,144 B
    unsigned short* WoT   = (unsigned short*)(ws + 101056512);     //    131,072 B
    float*          biasb = (float*)(ws + 101187584);              //    524,288 B
    u64*            maskp = (u64*)(ws + 101711872);                //  1,048,576 B
    float*          bqs   = (float*)(ws + 102760448);              //      1,024 B

    prep_weights<<<1024, 256, 0, stream>>>(Wq, Wkv, Wo, WqT, WkvT, WoT);
    prep_bias<<<513, 256, 0, stream>>>(rel, bq, biasb, bqs);
    prep_mask<<<512, 256, 0, stream>>>(mask, maskp);

    // Q = x @ (Wq*scale) + bq*scale -> bf16 [131072, 256]  (weight-stationary)
    gemm_ws<true, true><<<256, 512, 0, stream>>>(
        (const void*)x, WqT, bqs, (void*)Qbuf);
    // KV = z @ Wkv + bkv -> bf16 [32768, 512]
    gemm_proj<true, true><<<dim3(4, 256), 256, 0, stream>>>(
        (const void*)z, WkvT, bkv, (void*)KVbuf, 32768, 512, 256);
    // fused window attention (in-place into Qbuf)
    win_attn<<<dim3(64, 8, 8), 256, 0, stream>>>(Qbuf, KVbuf, maskp, biasb);
    // out = attn @ Wo + bo -> f32  (weight-stationary)
    gemm_ws<false, false><<<256, 512, 0, stream>>>(
        (const void*)Qbuf, WoT, bo, (void*)out);
}